// Round 1
// baseline (286.347 us; speedup 1.0000x reference)
//
#include <hip/hip_runtime.h>

// Dims (fixed by the problem): in_f=128, hid=16, out_c=16
#define IN_F 128
#define HID  16

// ---------------------------------------------------------------------------
// Tiny precompute: CA = W2 @ Wmlp[:128], CB = W2 @ Wmlp[128:],
// cbias = b2@Wmlp[:128] + b2@Wmlp[128:] + bmlp.   One block, 256 threads.
// ---------------------------------------------------------------------------
__global__ void precompute_kernel(const float* __restrict__ W2,    // [16][128]
                                  const float* __restrict__ b2,    // [128]
                                  const float* __restrict__ Wmlp,  // [256][16]
                                  const float* __restrict__ bmlp,  // [16]
                                  float* __restrict__ CA,          // [16][16]
                                  float* __restrict__ CB,          // [16][16]
                                  float* __restrict__ cbias) {     // [16]
    int t = threadIdx.x;          // 256 threads: (j, c)
    int j = t >> 4, c = t & 15;
    float sa = 0.f, sb = 0.f;
    for (int k = 0; k < 128; ++k) {
        float w = W2[j * 128 + k];
        sa += w * Wmlp[k * 16 + c];
        sb += w * Wmlp[(128 + k) * 16 + c];
    }
    CA[j * 16 + c] = sa;
    CB[j * 16 + c] = sb;
    if (j == 0) {
        float s = bmlp[c];
        for (int k = 0; k < 128; ++k)
            s += b2[k] * (Wmlp[k * 16 + c] + Wmlp[(128 + k) * 16 + c]);
        cbias[c] = s;
    }
}

// ---------------------------------------------------------------------------
// y = x @ W1   ([N,128] @ [128,16] -> [N,16])
// Block = 256 threads = 16 nodes x 16 outputs. x rows staged in LDS (coalesced
// float4), W1 staged in LDS.
// ---------------------------------------------------------------------------
__global__ void xw1_kernel(const float* __restrict__ x,
                           const float* __restrict__ W1,  // [128][16]
                           float* __restrict__ y, int N) {
    __shared__ float W1s[128 * 16];
    __shared__ float xs[16][128];
    int tid = threadIdx.x;
    // W1: 2048 floats = 512 float4
    const float4* W14 = (const float4*)W1;
    float4* W1s4 = (float4*)W1s;
    for (int i = tid; i < 512; i += 256) W1s4[i] = W14[i];
    // 16 rows of x, 32 float4 each
    int nblk = blockIdx.x * 16;
    const float4* x4 = (const float4*)x;
    float4* xs4 = (float4*)&xs[0][0];
    for (int i = tid; i < 512; i += 256) {
        int row = nblk + (i >> 5);
        xs4[i] = (row < N) ? x4[(size_t)row * 32 + (i & 31)]
                           : make_float4(0.f, 0.f, 0.f, 0.f);
    }
    __syncthreads();
    int nl = tid >> 4, j = tid & 15;
    int n = nblk + nl;
    if (n >= N) return;
    float acc = 0.f;
    const float* xr = &xs[nl][0];
    #pragma unroll 8
    for (int k = 0; k < 128; ++k) acc += xr[k] * W1s[k * 16 + j];
    y[(size_t)n * 16 + j] = acc;
}

// ---------------------------------------------------------------------------
// Edge scatter-add: agg[dst[e]][j] += v[src[e]][j]  (16 lanes per edge).
// Optionally accumulates in-degree (layer-1 pass only).
// ---------------------------------------------------------------------------
__global__ void edge_agg_kernel(const int* __restrict__ src,
                                const int* __restrict__ dst,
                                const float* __restrict__ v,   // [N][16]
                                float* __restrict__ agg,       // [N][16]
                                float* __restrict__ deg,       // [N] or null
                                long long total) {             // E*16
    long long gid = (long long)blockIdx.x * blockDim.x + threadIdx.x;
    if (gid >= total) return;
    int e = (int)(gid >> 4), j = (int)(gid & 15);
    int s = src[e], d = dst[e];
    atomicAdd(&agg[(size_t)d * 16 + j], v[(size_t)s * 16 + j]);
    if (deg != nullptr && j == 0) atomicAdd(&deg[d], 1.0f);
}

// ---------------------------------------------------------------------------
// h1 = relu((agg1 + y) * inv(deg+1) + b1); also store invdeg.
// ---------------------------------------------------------------------------
__global__ void h1_kernel(const float* __restrict__ agg1,
                          const float* __restrict__ y,
                          const float* __restrict__ deg,
                          const float* __restrict__ b1,   // [16]
                          float* __restrict__ h1,
                          float* __restrict__ invdeg, int N) {
    int gid = blockIdx.x * 256 + threadIdx.x;
    if (gid >= N * 16) return;
    int n = gid >> 4, j = gid & 15;
    float inv = 1.0f / (deg[n] + 1.0f);
    float val = (agg1[gid] + y[gid]) * inv + b1[j];
    h1[gid] = val > 0.f ? val : 0.f;
    if (j == 0) invdeg[n] = inv;
}

// ---------------------------------------------------------------------------
// Per node: g = (agg2 + h1) * invdeg;  su = g@CA;  sv = g@CB.
// Block = 256 threads = 16 nodes x 16 outputs; g shared via LDS.
// ---------------------------------------------------------------------------
__global__ void node_score_kernel(const float* __restrict__ agg2,
                                  const float* __restrict__ h1,
                                  const float* __restrict__ invdeg,
                                  const float* __restrict__ CA,  // [16][16]
                                  const float* __restrict__ CB,  // [16][16]
                                  float* __restrict__ su,
                                  float* __restrict__ sv, int N) {
    __shared__ float CAs[256], CBs[256];
    __shared__ float gs[16][17];
    int tid = threadIdx.x;
    CAs[tid] = CA[tid];
    CBs[tid] = CB[tid];
    int nl = tid >> 4, c = tid & 15;
    int n = blockIdx.x * 16 + nl;
    float g = 0.f;
    if (n < N) {
        int gid = n * 16 + c;
        g = (agg2[gid] + h1[gid]) * invdeg[n];
    }
    gs[nl][c] = g;
    __syncthreads();
    if (n >= N) return;
    float sa = 0.f, sb = 0.f;
    #pragma unroll
    for (int j = 0; j < 16; ++j) {
        float gj = gs[nl][j];
        sa += gj * CAs[j * 16 + c];
        sb += gj * CBs[j * 16 + c];
    }
    su[(size_t)n * 16 + c] = sa;
    sv[(size_t)n * 16 + c] = sb;
}

// ---------------------------------------------------------------------------
// Final per-edge score: out[e][c] = su[src[e]][c] + sv[dst[e]][c] + cbias[c]
// ---------------------------------------------------------------------------
__global__ void score_kernel(const int* __restrict__ src,
                             const int* __restrict__ dst,
                             const float* __restrict__ su,
                             const float* __restrict__ sv,
                             const float* __restrict__ cbias,
                             float* __restrict__ out,
                             long long total) {   // E*16
    long long gid = (long long)blockIdx.x * 256 + threadIdx.x;
    if (gid >= total) return;
    int e = (int)(gid >> 4), c = (int)(gid & 15);
    out[gid] = su[(size_t)src[e] * 16 + c] + sv[(size_t)dst[e] * 16 + c] + cbias[c];
}

// ---------------------------------------------------------------------------
extern "C" void kernel_launch(void* const* d_in, const int* in_sizes, int n_in,
                              void* d_out, int out_size, void* d_ws, size_t ws_size,
                              hipStream_t stream) {
    const float* x    = (const float*)d_in[0];
    const int*   src  = (const int*)  d_in[1];
    const int*   dst  = (const int*)  d_in[2];
    const float* W1   = (const float*)d_in[3];
    const float* b1   = (const float*)d_in[4];
    const float* W2   = (const float*)d_in[5];
    const float* b2   = (const float*)d_in[6];
    const float* Wmlp = (const float*)d_in[7];
    const float* bmlp = (const float*)d_in[8];
    float* out = (float*)d_out;

    const int N = in_sizes[0] / IN_F;   // 50000
    const int E = in_sizes[1];          // 800000

    // Workspace layout (floats). agg1/agg2/deg contiguous at front -> one memset.
    float* ws     = (float*)d_ws;
    float* agg1   = ws;                        // N*16
    float* agg2   = ws + (size_t)N * 16;       // N*16
    float* deg    = ws + (size_t)N * 32;       // N
    float* y      = ws + (size_t)N * 33;       // N*16
    float* h1     = ws + (size_t)N * 49;       // N*16
    float* su     = ws + (size_t)N * 65;       // N*16
    float* sv     = ws + (size_t)N * 81;       // N*16
    float* invdeg = ws + (size_t)N * 97;       // N
    float* CA     = ws + (size_t)N * 98;       // 256
    float* CB     = CA + 256;                  // 256
    float* cbias  = CB + 256;                  // 16

    // Zero the atomic-accumulated regions (ws is re-poisoned to 0xAA each call).
    hipMemsetAsync(d_ws, 0, (size_t)N * 33 * sizeof(float), stream);

    const long long totalE16 = (long long)E * 16;
    const int edgeBlocks = (int)((totalE16 + 255) / 256);
    const int nodeBlocks16 = (N + 15) / 16;       // 16 nodes per block
    const int elemBlocks = (N * 16 + 255) / 256;

    precompute_kernel<<<1, 256, 0, stream>>>(W2, b2, Wmlp, bmlp, CA, CB, cbias);
    xw1_kernel<<<nodeBlocks16, 256, 0, stream>>>(x, W1, y, N);
    edge_agg_kernel<<<edgeBlocks, 256, 0, stream>>>(src, dst, y, agg1, deg, totalE16);
    h1_kernel<<<elemBlocks, 256, 0, stream>>>(agg1, y, deg, b1, h1, invdeg, N);
    edge_agg_kernel<<<edgeBlocks, 256, 0, stream>>>(src, dst, h1, agg2, nullptr, totalE16);
    node_score_kernel<<<nodeBlocks16, 256, 0, stream>>>(agg2, h1, invdeg, CA, CB, su, sv, N);
    score_kernel<<<edgeBlocks, 256, 0, stream>>>(src, dst, su, sv, cbias, out, totalE16);
}